// Round 1
// baseline (931.673 us; speedup 1.0000x reference)
//
#include <hip/hip_runtime.h>
#include <cstddef>

#define NROWS 8192
constexpr float BN_EPS = 1e-5f;

// ---- workspace layout (floats) ----
constexpr size_t OFF_Y   = 0;                     // 8192*28 (y1/y2/y3)
constexpr size_t OFF_S   = OFF_Y  + 8192*28;      // 8192*28 (spmm accum / u in-place / T4)
constexpr size_t OFF_Z   = OFF_S  + 8192*28;      // 8192*8
constexpr size_t OFF_SL  = OFF_Z  + 8192*8;       // 8192*20
constexpr size_t OFF_ST1 = OFF_SL + 8192*20;      // 32 (sum, sumsq)
constexpr size_t OFF_ST2 = OFF_ST1 + 32;          // 32
constexpr size_t OFF_HSM = OFF_ST2 + 32;          // 160  (s_l^T z)
constexpr size_t OFF_A   = OFF_HSM + 160;         // 400  (s_l^T adj s_l)

// ============================================================
// skinny SPMM: S[row, 0:C] += adj[row, jrange] @ y[jrange, 0:C]
// grid = 32 row-blocks * 16 j-chunks; block = 256 threads.
// adj tile [256 rows x 64 j] staged in LDS with 4B XOR swizzle so that
// column reads (lanes = rows) are bank-conflict-free. y rows are
// wave-uniform -> scalar loads.
// ============================================================
template<int C>
__global__ __launch_bounds__(256)
void k_spmm(const float* __restrict__ adj, const float* __restrict__ y,
            float* __restrict__ S)
{
    __shared__ float lds[256 * 64];   // 64 KiB
    const int t    = threadIdx.x;
    const int rb   = blockIdx.x & 31;   // 32 row blocks
    const int jc   = blockIdx.x >> 5;   // 16 j chunks
    const int row0 = rb * 256;
    const int jbase = jc * 512;

    float acc[C];
#pragma unroll
    for (int k = 0; k < C; ++k) acc[k] = 0.f;

    const int colq = t & 15;   // float4 index along j
    const int rsub = t >> 4;   // 0..15
    const int swc  = t & 31;   // read swizzle for this thread's row

    for (int tile = 0; tile < 8; ++tile) {
        const int j0 = jbase + tile * 64;
        __syncthreads();
        // stage: issue all 16 loads, then write (gives MLP)
        float4 v[16];
#pragma unroll
        for (int it = 0; it < 16; ++it) {
            const int r = rsub + it * 16;
            v[it] = *reinterpret_cast<const float4*>(
                &adj[(size_t)(row0 + r) * NROWS + j0 + colq * 4]);
        }
#pragma unroll
        for (int it = 0; it < 16; ++it) {
            const int r  = rsub + it * 16;
            const int sw = r & 31;
            const int jj = colq * 4;
            lds[r * 64 + ((jj + 0) ^ sw)] = v[it].x;
            lds[r * 64 + ((jj + 1) ^ sw)] = v[it].y;
            lds[r * 64 + ((jj + 2) ^ sw)] = v[it].z;
            lds[r * 64 + ((jj + 3) ^ sw)] = v[it].w;
        }
        __syncthreads();
        const float* __restrict__ yb   = y + (size_t)j0 * C;
        const float* __restrict__ lrow = lds + t * 64;
#pragma unroll 4
        for (int jj = 0; jj < 64; ++jj) {
            const float aval = lrow[jj ^ swc];
#pragma unroll
            for (int k = 0; k < C; ++k)
                acc[k] = fmaf(aval, yb[jj * C + k], acc[k]);
        }
    }
#pragma unroll
    for (int k = 0; k < C; ++k)
        atomicAdd(&S[(size_t)(row0 + t) * C + k], acc[k]);
}

// ---- y1 = x @ W1 ----
__global__ __launch_bounds__(256)
void k_y1(const float* __restrict__ x, const float* __restrict__ W1,
          float* __restrict__ y)
{
    const int row = blockIdx.x * 256 + threadIdx.x;
    float xr[18];
#pragma unroll
    for (int d = 0; d < 18; ++d) xr[d] = x[row * 18 + d];
#pragma unroll
    for (int k = 0; k < 16; ++k) {
        float a = 0.f;
#pragma unroll
        for (int d = 0; d < 18; ++d) a = fmaf(xr[d], W1[d * 16 + k], a);
        y[row * 16 + k] = a;
    }
}

// ---- u = relu(S + b) in-place; accumulate column sum/sumsq ----
__global__ __launch_bounds__(256)
void k_fin_relu_stats(float* __restrict__ S, const float* __restrict__ bias,
                      float* __restrict__ stats)
{
    const int t  = threadIdx.x;
    const int k  = t & 15;
    const int rg = t >> 4;
    float s = 0.f, ss = 0.f;
    for (int r = blockIdx.x * 16 + rg; r < NROWS; r += 1024) {
        float v = S[r * 16 + k] + bias[k];
        v = fmaxf(v, 0.f);
        S[r * 16 + k] = v;
        s += v; ss += v * v;
    }
    __shared__ float ls[16][17], lss[16][17];
    ls[rg][k] = s; lss[rg][k] = ss;
    __syncthreads();
    if (t < 16) {
        float a = 0.f, b = 0.f;
        for (int g = 0; g < 16; ++g) { a += ls[g][t]; b += lss[g][t]; }
        atomicAdd(&stats[t], a);
        atomicAdd(&stats[16 + t], b);
    }
}

// ---- y = BN(u) @ [Wa | Wb]  (BN folded per-column scale/shift) ----
template<int COA, int COB>
__global__ __launch_bounds__(256)
void k_bn_matmul(const float* __restrict__ u, const float* __restrict__ stats,
                 const float* __restrict__ g, const float* __restrict__ bt,
                 const float* __restrict__ Wa, const float* __restrict__ Wb,
                 float* __restrict__ y)
{
    const int row = blockIdx.x * 256 + threadIdx.x;
    constexpr int CO = COA + COB;
    float h[16];
#pragma unroll
    for (int k = 0; k < 16; ++k) {
        const float m   = stats[k] * (1.f / NROWS);
        const float var = stats[16 + k] * (1.f / NROWS) - m * m;
        const float sc  = g[k] * rsqrtf(var + BN_EPS);
        const float sh  = bt[k] - m * sc;
        h[k] = fmaf(u[row * 16 + k], sc, sh);
    }
#pragma unroll
    for (int co = 0; co < COA; ++co) {
        float a = 0.f;
#pragma unroll
        for (int k = 0; k < 16; ++k) a = fmaf(h[k], Wa[k * COA + co], a);
        y[(size_t)row * CO + co] = a;
    }
#pragma unroll
    for (int co = 0; co < COB; ++co) {
        float a = 0.f;
#pragma unroll
        for (int k = 0; k < 16; ++k) a = fmaf(h[k], Wb[k * COB + co], a);
        y[(size_t)row * CO + COA + co] = a;
    }
}

// ---- z = S3[:, :8]+be1 ; s_l = softmax(S3[:, 8:28]+bp1) ; hsm += s_l^T z ----
__global__ __launch_bounds__(256)
void k_fin3(const float* __restrict__ S3, const float* __restrict__ be1,
            const float* __restrict__ bp1, float* __restrict__ z,
            float* __restrict__ sl, float* __restrict__ hsm)
{
    __shared__ float szl[256 * 8];
    __shared__ float ssl[256 * 20];
    const int t = threadIdx.x;
    const int row = blockIdx.x * 256 + t;
    float zr[8];
#pragma unroll
    for (int k = 0; k < 8; ++k) {
        zr[k] = S3[(size_t)row * 28 + k] + be1[k];
        z[(size_t)row * 8 + k] = zr[k];
        szl[t * 8 + k] = zr[k];
    }
    float s[20];
    float mx = -1e30f;
#pragma unroll
    for (int k = 0; k < 20; ++k) {
        s[k] = S3[(size_t)row * 28 + 8 + k] + bp1[k];
        mx = fmaxf(mx, s[k]);
    }
    float se = 0.f;
#pragma unroll
    for (int k = 0; k < 20; ++k) { s[k] = expf(s[k] - mx); se += s[k]; }
    const float inv = 1.f / se;
#pragma unroll
    for (int k = 0; k < 20; ++k) {
        s[k] *= inv;
        sl[(size_t)row * 20 + k] = s[k];
        ssl[t * 20 + k] = s[k];
    }
    __syncthreads();
    if (t < 160) {
        const int p = t >> 3, q = t & 7;
        float a = 0.f;
        for (int r = 0; r < 256; ++r) a = fmaf(ssl[r * 20 + p], szl[r * 8 + q], a);
        atomicAdd(&hsm[t], a);
    }
}

// ---- a[p,q] += sum_r sl[r,p] * T4[r,q]  (T4 = adj @ sl) ----
__global__ __launch_bounds__(256)
void k_fin4(const float* __restrict__ T4, const float* __restrict__ sl,
            float* __restrict__ a_g)
{
    __shared__ float stt[256 * 20];
    __shared__ float ssl[256 * 20];
    const int t = threadIdx.x;
    const int base = blockIdx.x * 256 * 20;
    for (int i = t; i < 256 * 20; i += 256) {
        stt[i] = T4[base + i];
        ssl[i] = sl[base + i];
    }
    __syncthreads();
    for (int pair = t; pair < 400; pair += 256) {
        const int p = pair / 20, q = pair % 20;
        float a = 0.f;
        for (int r = 0; r < 256; ++r) a = fmaf(ssl[r * 20 + p], stt[r * 20 + q], a);
        atomicAdd(&a_g[pair], a);
    }
}

// ---- final tiny stage: h=BN(relu(a@(hsm@W3)+b3)); out=colsum(a@(h@We2)+be2) ----
__global__ __launch_bounds__(256)
void k_final(const float* __restrict__ hsm, const float* __restrict__ a_g,
             const float* __restrict__ W3, const float* __restrict__ b3,
             const float* __restrict__ g3, const float* __restrict__ bt3,
             const float* __restrict__ We2, const float* __restrict__ be2,
             float* __restrict__ out)
{
    __shared__ float m1[160], qb[160], hb[160], sc[8], sh[8];
    const int t = threadIdx.x;
    const int p = t >> 3, k = t & 7;
    if (t < 160) {
        float a = 0.f;
        for (int j = 0; j < 8; ++j) a = fmaf(hsm[p * 8 + j], W3[j * 8 + k], a);
        m1[t] = a;
    }
    __syncthreads();
    if (t < 160) {
        float a = b3[k];
        for (int j = 0; j < 20; ++j) a = fmaf(a_g[p * 20 + j], m1[j * 8 + k], a);
        qb[t] = fmaxf(a, 0.f);
    }
    __syncthreads();
    if (t < 8) {
        float m = 0.f, v = 0.f;
        for (int r = 0; r < 20; ++r) { float q = qb[r * 8 + t]; m += q; v += q * q; }
        m *= (1.f / 20.f); v = v * (1.f / 20.f) - m * m;
        const float s = g3[t] * rsqrtf(v + BN_EPS);
        sc[t] = s; sh[t] = bt3[t] - m * s;
    }
    __syncthreads();
    if (t < 160) hb[t] = fmaf(qb[t], sc[k], sh[k]);
    __syncthreads();
    if (t < 160) {
        float a = 0.f;
        for (int j = 0; j < 8; ++j) a = fmaf(hb[p * 8 + j], We2[j * 8 + k], a);
        m1[t] = a;  // reuse as m2
    }
    __syncthreads();
    if (t < 160) {
        float a = be2[k];
        for (int j = 0; j < 20; ++j) a = fmaf(a_g[p * 20 + j], m1[j * 8 + k], a);
        qb[t] = a;  // z2
    }
    __syncthreads();
    if (t < 8) {
        float a = 0.f;
        for (int r = 0; r < 20; ++r) a += qb[r * 8 + t];
        out[t] = a;
    }
}

extern "C" void kernel_launch(void* const* d_in, const int* in_sizes, int n_in,
                              void* d_out, int out_size, void* d_ws, size_t ws_size,
                              hipStream_t stream)
{
    const float* x   = (const float*)d_in[0];
    const float* adj = (const float*)d_in[1];
    const float* W1  = (const float*)d_in[2];
    const float* b1  = (const float*)d_in[3];
    const float* W2  = (const float*)d_in[4];
    const float* b2  = (const float*)d_in[5];
    const float* We1 = (const float*)d_in[6];
    const float* be1 = (const float*)d_in[7];
    const float* Wp1 = (const float*)d_in[8];
    const float* bp1 = (const float*)d_in[9];
    const float* W3  = (const float*)d_in[10];
    const float* b3  = (const float*)d_in[11];
    const float* We2 = (const float*)d_in[12];
    const float* be2 = (const float*)d_in[13];
    const float* g1  = (const float*)d_in[14];
    const float* bt1 = (const float*)d_in[15];
    const float* g2  = (const float*)d_in[16];
    const float* bt2 = (const float*)d_in[17];
    const float* g3  = (const float*)d_in[18];
    const float* bt3 = (const float*)d_in[19];

    float* ws  = (float*)d_ws;
    float* Y   = ws + OFF_Y;
    float* S   = ws + OFF_S;
    float* Z   = ws + OFF_Z;
    float* SL  = ws + OFF_SL;
    float* ST1 = ws + OFF_ST1;
    float* ST2 = ws + OFF_ST2;
    float* HSM = ws + OFF_HSM;
    float* AG  = ws + OFF_A;
    float* out = (float*)d_out;

    const dim3 blk(256);

    // zero all small accumulators (stats1, stats2, hsm, a) in one shot
    hipMemsetAsync(ST1, 0, (32 + 32 + 160 + 400) * sizeof(float), stream);

    // ---- layer 1: u1 = relu(adj @ (x@W1) + b1), BN stats ----
    hipMemsetAsync(S, 0, (size_t)NROWS * 16 * sizeof(float), stream);
    k_y1<<<32, blk, 0, stream>>>(x, W1, Y);
    k_spmm<16><<<512, blk, 0, stream>>>(adj, Y, S);
    k_fin_relu_stats<<<64, blk, 0, stream>>>(S, b1, ST1);
    k_bn_matmul<16, 0><<<32, blk, 0, stream>>>(S, ST1, g1, bt1, W2, nullptr, Y);

    // ---- layer 2 ----
    hipMemsetAsync(S, 0, (size_t)NROWS * 16 * sizeof(float), stream);
    k_spmm<16><<<512, blk, 0, stream>>>(adj, Y, S);
    k_fin_relu_stats<<<64, blk, 0, stream>>>(S, b2, ST2);
    k_bn_matmul<8, 20><<<32, blk, 0, stream>>>(S, ST2, g2, bt2, We1, Wp1, Y);

    // ---- pool linears: S3 = adj @ [h@We1 | h@Wp1] ----
    hipMemsetAsync(S, 0, (size_t)NROWS * 28 * sizeof(float), stream);
    k_spmm<28><<<512, blk, 0, stream>>>(adj, Y, S);
    k_fin3<<<32, blk, 0, stream>>>(S, be1, bp1, Z, SL, HSM);

    // ---- T4 = adj @ s_l ; a = s_l^T T4 ----
    hipMemsetAsync(S, 0, (size_t)NROWS * 20 * sizeof(float), stream);
    k_spmm<20><<<512, blk, 0, stream>>>(adj, SL, S);
    k_fin4<<<32, blk, 0, stream>>>(S, SL, AG);

    // ---- tiny final stage ----
    k_final<<<1, blk, 0, stream>>>(HSM, AG, W3, b3, g3, bt3, We2, be2, out);
}

// Round 2
// 249.360 us; speedup vs baseline: 3.7363x; 3.7363x over previous
//
#include <hip/hip_runtime.h>
#include <cstddef>

#define NROWS 8192
constexpr float BN_EPS = 1e-5f;

typedef __attribute__((ext_vector_type(8))) short bf16x8;
typedef __attribute__((ext_vector_type(4))) float f32x4;

__device__ __forceinline__ unsigned short bf16u(float f) {
    unsigned u = __float_as_uint(f);
    u += 0x7FFFu + ((u >> 16) & 1u);
    return (unsigned short)(u >> 16);
}

// ---- workspace layout (float offsets) ----
constexpr size_t OFF_P   = 0;                                   // 16*8192*32
constexpr size_t OFF_YP  = OFF_P   + (size_t)16 * NROWS * 32;   // 8192*32 ushort
constexpr size_t OFF_SLP = OFF_YP  + (size_t)NROWS * 32 / 2;    // 8192*32 ushort
constexpr size_t OFF_U   = OFF_SLP + (size_t)NROWS * 32 / 2;    // 8192*16 f32
constexpr size_t OFF_S3  = OFF_U   + (size_t)NROWS * 16;        // 8192*28 f32
constexpr size_t OFF_SL  = OFF_S3  + (size_t)NROWS * 28;        // 8192*20 f32
constexpr size_t OFF_T4  = OFF_SL  + (size_t)NROWS * 20;        // 8192*20 f32
constexpr size_t OFF_ST1 = OFF_T4  + (size_t)NROWS * 20;        // 32
constexpr size_t OFF_ST2 = OFF_ST1 + 32;                        // 32
constexpr size_t OFF_HSM = OFF_ST2 + 32;                        // 160
constexpr size_t OFF_AG  = OFF_HSM + 160;                       // 400
constexpr size_t OFF_END_SMALL = OFF_AG + 400;
constexpr size_t OFF_ADJB = (OFF_END_SMALL + 15) & ~(size_t)15; // 8192*8192 bf16
constexpr size_t NEED_FULL_BYTES = (OFF_ADJB + (size_t)NROWS * NROWS / 2) * 4;

// ============================================================
// Streaming MFMA spmm: P[kc][rows][CP] = adj[rows, kchunk] @ ypacked
// grid = 64 row-blocks x 16 k-chunks, 256 thr (4 waves), wave = 32 rows.
// MODE 0: read bf16 adj; 1: read fp32 adj (convert in reg);
//      2: read fp32 adj, convert, ALSO store bf16 adj (fused convert).
// A-frag: lane holds row=lane&15 (+16*mtile), k=(lane>>4)*8 .. +7.
// B pre-packed in fragment order by producer kernels.
// ============================================================
template<int NT, int MODE>
__global__ __launch_bounds__(256)
void k_spmm(const float* __restrict__ adjf, unsigned short* __restrict__ adjb,
            const unsigned short* __restrict__ ypu, float* __restrict__ P)
{
    constexpr int CP = NT * 16;
    const int rb   = blockIdx.x & 63;
    const int kc   = blockIdx.x >> 6;
    const int lane = threadIdx.x & 63;
    const int wv   = threadIdx.x >> 6;
    const int row0 = rb * 128 + wv * 32;
    const int k0   = kc * 512;
    const int rA   = lane & 15;
    const int kA   = (lane >> 4) * 8;
    const bf16x8* yp = (const bf16x8*)ypu;

    f32x4 acc[2][NT];
#pragma unroll
    for (int m = 0; m < 2; ++m)
#pragma unroll
        for (int n = 0; n < NT; ++n) acc[m][n] = (f32x4){0.f, 0.f, 0.f, 0.f};

    const size_t offA0 = (size_t)(row0 + rA) * NROWS + k0 + kA;
    const size_t offA1 = offA0 + (size_t)16 * NROWS;

    auto LA = [&](int m, int s) -> bf16x8 {
        const size_t o = (m ? offA1 : offA0) + (size_t)s * 32;
        if constexpr (MODE == 0) {
            return *(const bf16x8*)(adjb + o);
        } else {
            const float* p = adjf + o;
            const float4 u = *(const float4*)p;
            const float4 v = *(const float4*)(p + 4);
            bf16x8 t;
            t[0] = (short)bf16u(u.x); t[1] = (short)bf16u(u.y);
            t[2] = (short)bf16u(u.z); t[3] = (short)bf16u(u.w);
            t[4] = (short)bf16u(v.x); t[5] = (short)bf16u(v.y);
            t[6] = (short)bf16u(v.z); t[7] = (short)bf16u(v.w);
            if constexpr (MODE == 2) *(bf16x8*)(adjb + o) = t;
            return t;
        }
    };
    auto LB = [&](int n, int s) -> bf16x8 {
        return yp[((size_t)((kc * 16 + s) * NT + n)) * 64 + lane];
    };

    bf16x8 a0 = LA(0, 0), a1 = LA(1, 0);
    bf16x8 b0 = LB(0, 0), b1;
    if constexpr (NT == 2) b1 = LB(1, 0);

#pragma unroll
    for (int s = 0; s < 16; ++s) {
        bf16x8 na0, na1, nb0, nb1;
        if (s < 15) {
            na0 = LA(0, s + 1); na1 = LA(1, s + 1);
            nb0 = LB(0, s + 1);
            if constexpr (NT == 2) nb1 = LB(1, s + 1);
        }
        acc[0][0] = __builtin_amdgcn_mfma_f32_16x16x32_bf16(a0, b0, acc[0][0], 0, 0, 0);
        acc[1][0] = __builtin_amdgcn_mfma_f32_16x16x32_bf16(a1, b0, acc[1][0], 0, 0, 0);
        if constexpr (NT == 2) {
            acc[0][1] = __builtin_amdgcn_mfma_f32_16x16x32_bf16(a0, b1, acc[0][1], 0, 0, 0);
            acc[1][1] = __builtin_amdgcn_mfma_f32_16x16x32_bf16(a1, b1, acc[1][1], 0, 0, 0);
        }
        if (s < 15) { a0 = na0; a1 = na1; b0 = nb0; if constexpr (NT == 2) b1 = nb1; }
    }

    // epilogue: D layout col=lane&15, row=(lane>>4)*4+reg  [m89]
    float* Pk = P + ((size_t)kc * NROWS + row0) * CP;
    const int drow = (lane >> 4) * 4;
    const int dcol = lane & 15;
#pragma unroll
    for (int m = 0; m < 2; ++m)
#pragma unroll
        for (int n = 0; n < NT; ++n)
#pragma unroll
            for (int r = 0; r < 4; ++r)
                Pk[(size_t)(m * 16 + drow + r) * CP + n * 16 + dcol] = acc[m][n][r];
}

// ---- y1 = x @ W1, written directly in B-fragment bf16 layout (NT=1) ----
__global__ __launch_bounds__(256)
void k_y1_pack(const float* __restrict__ x, const float* __restrict__ W1,
               unsigned short* __restrict__ yp)
{
    const int j = blockIdx.x * 256 + threadIdx.x;
    float xr[18];
#pragma unroll
    for (int d = 0; d < 18; ++d) xr[d] = x[j * 18 + d];
    const int kb = j >> 5, lhi = ((j & 31) >> 3) << 4, idx = j & 7;
#pragma unroll
    for (int c = 0; c < 16; ++c) {
        float a = 0.f;
#pragma unroll
        for (int d = 0; d < 18; ++d) a = fmaf(xr[d], W1[d * 16 + c], a);
        yp[((size_t)kb * 64 + (lhi | c)) * 8 + idx] = bf16u(a);
    }
}

// ---- sum 16 partials + bias + relu -> U; accumulate BN col sum/sumsq ----
__global__ __launch_bounds__(256)
void k_reduce16(const float* __restrict__ P, const float* __restrict__ bias,
                float* __restrict__ U, float* __restrict__ stats)
{
    const int t = threadIdx.x, col = t & 15, rg = t >> 4;
    float s = 0.f, ss = 0.f;
    for (int r = blockIdx.x * 16 + rg; r < NROWS; r += 1024) {
        float v = bias[col];
#pragma unroll
        for (int kc = 0; kc < 16; ++kc) v += P[((size_t)kc * NROWS + r) * 16 + col];
        v = fmaxf(v, 0.f);
        U[r * 16 + col] = v;
        s += v; ss += v * v;
    }
    __shared__ float ls[16][17], lss[16][17];
    ls[rg][col] = s; lss[rg][col] = ss;
    __syncthreads();
    if (t < 16) {
        float a = 0.f, b = 0.f;
        for (int g = 0; g < 16; ++g) { a += ls[g][t]; b += lss[g][t]; }
        atomicAdd(&stats[t], a);
        atomicAdd(&stats[16 + t], b);
    }
}

// ---- sum 16 partials (CP=32) -> compact CO columns, no bias/relu ----
template<int CO>
__global__ __launch_bounds__(256)
void k_reduce32(const float* __restrict__ P, float* __restrict__ out)
{
    const int col = threadIdx.x & 31, rg = threadIdx.x >> 5;
    if (col >= CO) return;
    for (int r = blockIdx.x * 8 + rg; r < NROWS; r += 1024) {
        float v = 0.f;
#pragma unroll
        for (int kc = 0; kc < 16; ++kc) v += P[((size_t)kc * NROWS + r) * 32 + col];
        out[(size_t)r * CO + col] = v;
    }
}

// ---- h = BN(U); y = h @ [Wa|Wb]; write packed B-frag bf16, zero-pad ----
template<int COA, int COB, int NTO>
__global__ __launch_bounds__(256)
void k_bn_pack(const float* __restrict__ U, const float* __restrict__ stats,
               const float* __restrict__ g, const float* __restrict__ bt,
               const float* __restrict__ Wa, const float* __restrict__ Wb,
               unsigned short* __restrict__ yp)
{
    const int j = blockIdx.x * 256 + threadIdx.x;
    float h[16];
#pragma unroll
    for (int k = 0; k < 16; ++k) {
        const float m   = stats[k] * (1.f / NROWS);
        const float var = stats[16 + k] * (1.f / NROWS) - m * m;
        const float sc  = g[k] * rsqrtf(var + BN_EPS);
        h[k] = fmaf(U[j * 16 + k], sc, bt[k] - m * sc);
    }
    const int kb = j >> 5, lhi = ((j & 31) >> 3) << 4, idx = j & 7;
    auto slot = [&](int c) -> size_t {
        return ((size_t)(kb * NTO + (c >> 4)) * 64 + (lhi | (c & 15))) * 8 + idx;
    };
#pragma unroll
    for (int co = 0; co < COA; ++co) {
        float a = 0.f;
#pragma unroll
        for (int k = 0; k < 16; ++k) a = fmaf(h[k], Wa[k * COA + co], a);
        yp[slot(co)] = bf16u(a);
    }
#pragma unroll
    for (int co = 0; co < COB; ++co) {
        float a = 0.f;
#pragma unroll
        for (int k = 0; k < 16; ++k) a = fmaf(h[k], Wb[k * COB + co], a);
        yp[slot(COA + co)] = bf16u(a);
    }
#pragma unroll
    for (int c = COA + COB; c < NTO * 16; ++c) yp[slot(c)] = 0;
}

// ---- z=S3[:,:8]+be1; s_l=softmax(S3[:,8:28]+bp1); SL f32 + packed; hsm += s_l^T z ----
__global__ __launch_bounds__(256)
void k_fin3(const float* __restrict__ S3, const float* __restrict__ be1,
            const float* __restrict__ bp1, float* __restrict__ sl,
            unsigned short* __restrict__ slp, float* __restrict__ hsm)
{
    __shared__ float szl[256 * 8];
    __shared__ float ssl[256 * 20];
    const int t = threadIdx.x;
    const int row = blockIdx.x * 256 + t;
#pragma unroll
    for (int k = 0; k < 8; ++k) {
        const float z = S3[(size_t)row * 28 + k] + be1[k];
        szl[t * 8 + k] = z;
    }
    float s[20];
    float mx = -1e30f;
#pragma unroll
    for (int k = 0; k < 20; ++k) {
        s[k] = S3[(size_t)row * 28 + 8 + k] + bp1[k];
        mx = fmaxf(mx, s[k]);
    }
    float se = 0.f;
#pragma unroll
    for (int k = 0; k < 20; ++k) { s[k] = expf(s[k] - mx); se += s[k]; }
    const float inv = 1.f / se;
    const int kb = row >> 5, lhi = ((row & 31) >> 3) << 4, idx = row & 7;
    auto slot = [&](int c) -> size_t {
        return ((size_t)(kb * 2 + (c >> 4)) * 64 + (lhi | (c & 15))) * 8 + idx;
    };
#pragma unroll
    for (int k = 0; k < 20; ++k) {
        s[k] *= inv;
        sl[(size_t)row * 20 + k] = s[k];
        ssl[t * 20 + k] = s[k];
        slp[slot(k)] = bf16u(s[k]);
    }
#pragma unroll
    for (int c = 20; c < 32; ++c) slp[slot(c)] = 0;
    __syncthreads();
    if (t < 160) {
        const int p = t >> 3, q = t & 7;
        float a = 0.f;
        for (int r = 0; r < 256; ++r) a = fmaf(ssl[r * 20 + p], szl[r * 8 + q], a);
        atomicAdd(&hsm[t], a);
    }
}

// ---- a[p,q] += sum_r sl[r,p] * T4[r,q] ----
__global__ __launch_bounds__(256)
void k_fin4(const float* __restrict__ T4, const float* __restrict__ sl,
            float* __restrict__ a_g)
{
    __shared__ float stt[256 * 20];
    __shared__ float ssl[256 * 20];
    const int t = threadIdx.x;
    const int base = blockIdx.x * 256 * 20;
    for (int i = t; i < 256 * 20; i += 256) {
        stt[i] = T4[base + i];
        ssl[i] = sl[base + i];
    }
    __syncthreads();
    for (int pair = t; pair < 400; pair += 256) {
        const int p = pair / 20, q = pair % 20;
        float a = 0.f;
        for (int r = 0; r < 256; ++r) a = fmaf(ssl[r * 20 + p], stt[r * 20 + q], a);
        atomicAdd(&a_g[pair], a);
    }
}

// ---- tiny final stage ----
__global__ __launch_bounds__(256)
void k_final(const float* __restrict__ hsm, const float* __restrict__ a_g,
             const float* __restrict__ W3, const float* __restrict__ b3,
             const float* __restrict__ g3, const float* __restrict__ bt3,
             const float* __restrict__ We2, const float* __restrict__ be2,
             float* __restrict__ out)
{
    __shared__ float m1[160], qb[160], hb[160], sc[8], sh[8];
    const int t = threadIdx.x;
    const int p = t >> 3, k = t & 7;
    if (t < 160) {
        float a = 0.f;
        for (int j = 0; j < 8; ++j) a = fmaf(hsm[p * 8 + j], W3[j * 8 + k], a);
        m1[t] = a;
    }
    __syncthreads();
    if (t < 160) {
        float a = b3[k];
        for (int j = 0; j < 20; ++j) a = fmaf(a_g[p * 20 + j], m1[j * 8 + k], a);
        qb[t] = fmaxf(a, 0.f);
    }
    __syncthreads();
    if (t < 8) {
        float m = 0.f, v = 0.f;
        for (int r = 0; r < 20; ++r) { float q = qb[r * 8 + t]; m += q; v += q * q; }
        m *= (1.f / 20.f); v = v * (1.f / 20.f) - m * m;
        const float s = g3[t] * rsqrtf(v + BN_EPS);
        sc[t] = s; sh[t] = bt3[t] - m * s;
    }
    __syncthreads();
    if (t < 160) hb[t] = fmaf(qb[t], sc[k], sh[k]);
    __syncthreads();
    if (t < 160) {
        float a = 0.f;
        for (int j = 0; j < 8; ++j) a = fmaf(hb[p * 8 + j], We2[j * 8 + k], a);
        m1[t] = a;
    }
    __syncthreads();
    if (t < 160) {
        float a = be2[k];
        for (int j = 0; j < 20; ++j) a = fmaf(a_g[p * 20 + j], m1[j * 8 + k], a);
        qb[t] = a;
    }
    __syncthreads();
    if (t < 8) {
        float a = 0.f;
        for (int r = 0; r < 20; ++r) a += qb[r * 8 + t];
        out[t] = a;
    }
}

extern "C" void kernel_launch(void* const* d_in, const int* in_sizes, int n_in,
                              void* d_out, int out_size, void* d_ws, size_t ws_size,
                              hipStream_t stream)
{
    const float* x   = (const float*)d_in[0];
    const float* adj = (const float*)d_in[1];
    const float* W1  = (const float*)d_in[2];
    const float* b1  = (const float*)d_in[3];
    const float* W2  = (const float*)d_in[4];
    const float* b2  = (const float*)d_in[5];
    const float* We1 = (const float*)d_in[6];
    const float* be1 = (const float*)d_in[7];
    const float* Wp1 = (const float*)d_in[8];
    const float* bp1 = (const float*)d_in[9];
    const float* W3  = (const float*)d_in[10];
    const float* b3  = (const float*)d_in[11];
    const float* We2 = (const float*)d_in[12];
    const float* be2 = (const float*)d_in[13];
    const float* g1  = (const float*)d_in[14];
    const float* bt1 = (const float*)d_in[15];
    const float* g2  = (const float*)d_in[16];
    const float* bt2 = (const float*)d_in[17];
    const float* g3  = (const float*)d_in[18];
    const float* bt3 = (const float*)d_in[19];

    float* ws = (float*)d_ws;
    float* P  = ws + OFF_P;
    unsigned short* YP   = (unsigned short*)(ws + OFF_YP);
    unsigned short* SLP  = (unsigned short*)(ws + OFF_SLP);
    float* U   = ws + OFF_U;
    float* S3  = ws + OFF_S3;
    float* SL  = ws + OFF_SL;
    float* T4  = ws + OFF_T4;
    float* ST1 = ws + OFF_ST1;
    float* ST2 = ws + OFF_ST2;
    float* HSM = ws + OFF_HSM;
    float* AG  = ws + OFF_AG;
    unsigned short* ADJB = (unsigned short*)(ws + OFF_ADJB);
    float* out = (float*)d_out;

    const bool FULL = ws_size >= NEED_FULL_BYTES;
    const dim3 blk(256);

    // zero small accumulators (ST1, ST2, HSM, AG contiguous)
    hipMemsetAsync(ST1, 0, (32 + 32 + 160 + 400) * sizeof(float), stream);

    // ---- pass 1: U1 = relu(adj @ (x@W1) + b1); fused fp32->bf16 adj convert ----
    k_y1_pack<<<32, blk, 0, stream>>>(x, W1, YP);
    if (FULL) k_spmm<1, 2><<<1024, blk, 0, stream>>>(adj, ADJB, YP, P);
    else      k_spmm<1, 1><<<1024, blk, 0, stream>>>(adj, nullptr, YP, P);
    k_reduce16<<<64, blk, 0, stream>>>(P, b1, U, ST1);
    k_bn_pack<16, 0, 1><<<32, blk, 0, stream>>>(U, ST1, g1, bt1, W2, nullptr, YP);

    // ---- pass 2 ----
    if (FULL) k_spmm<1, 0><<<1024, blk, 0, stream>>>(nullptr, ADJB, YP, P);
    else      k_spmm<1, 1><<<1024, blk, 0, stream>>>(adj, nullptr, YP, P);
    k_reduce16<<<64, blk, 0, stream>>>(P, b2, U, ST2);
    k_bn_pack<8, 20, 2><<<32, blk, 0, stream>>>(U, ST2, g2, bt2, We1, Wp1, YP);

    // ---- pass 3: S3 = adj @ [h@We1 | h@Wp1] (28 cols) ----
    if (FULL) k_spmm<2, 0><<<1024, blk, 0, stream>>>(nullptr, ADJB, YP, P);
    else      k_spmm<2, 1><<<1024, blk, 0, stream>>>(adj, nullptr, YP, P);
    k_reduce32<28><<<128, blk, 0, stream>>>(P, S3);
    k_fin3<<<32, blk, 0, stream>>>(S3, be1, bp1, SL, SLP, HSM);

    // ---- pass 4: T4 = adj @ s_l ; a = s_l^T T4 ----
    if (FULL) k_spmm<2, 0><<<1024, blk, 0, stream>>>(nullptr, ADJB, SLP, P);
    else      k_spmm<2, 1><<<1024, blk, 0, stream>>>(adj, nullptr, SLP, P);
    k_reduce32<20><<<128, blk, 0, stream>>>(P, T4);
    k_fin4<<<32, blk, 0, stream>>>(T4, SL, AG);

    // ---- tiny final stage ----
    k_final<<<1, blk, 0, stream>>>(HSM, AG, W3, b3, g3, bt3, We2, be2, out);
}